// Round 1
// baseline (97.272 us; speedup 1.0000x reference)
//
#include <hip/hip_runtime.h>
#include <hip/hip_bf16.h>

#define EPSF 1e-5f

typedef __attribute__((ext_vector_type(8))) short bf16x8;
typedef __attribute__((ext_vector_type(4))) float f32x4;

__device__ __forceinline__ unsigned short f2bf(float f) {
  union { float f; unsigned u; } v; v.f = f;
  unsigned r = v.u + 0x7fffu + ((v.u >> 16) & 1u);
  return (unsigned short)(r >> 16);
}

__device__ __forceinline__ void gload_lds16(const void* g, void* l) {
  __builtin_amdgcn_global_load_lds(
      (const __attribute__((address_space(1))) void*)g,
      (__attribute__((address_space(3))) void*)l, 16, 0, 0);
}

// ---------------- prep: fold eval-BN into weights, cast to bf16 ----------------
__global__ void prep_kernel(const float* __restrict__ w1, const float* __restrict__ b1,
                            const float* __restrict__ g1, const float* __restrict__ be1,
                            const float* __restrict__ m1, const float* __restrict__ v1,
                            const float* __restrict__ w2, const float* __restrict__ b2,
                            const float* __restrict__ g2, const float* __restrict__ be2,
                            const float* __restrict__ m2, const float* __restrict__ v2,
                            unsigned short* __restrict__ w1f, unsigned short* __restrict__ w2f,
                            float* __restrict__ bias1, float* __restrict__ bias2) {
  int idx = blockIdx.x * blockDim.x + threadIdx.x;
  int stride = gridDim.x * blockDim.x;
  for (int i = idx; i < 2 * 256 * 4096; i += stride) {
    int mk = i >> 12;                       // m*256 + k
    float inv = g1[mk] * rsqrtf(v1[mk] + EPSF);
    w1f[i] = f2bf(w1[i] * inv);
  }
  for (int i = idx; i < 2 * 128 * 256; i += stride) {
    int mj = i >> 8;                        // m*128 + j
    float inv = g2[mj] * rsqrtf(v2[mj] + EPSF);
    w2f[i] = f2bf(w2[i] * inv);
  }
  if (idx < 512) {
    float inv = g1[idx] * rsqrtf(v1[idx] + EPSF);
    bias1[idx] = b1[idx] * inv + be1[idx] - m1[idx] * inv;
  }
  if (idx < 256) {
    float inv = g2[idx] * rsqrtf(v2[idx] + EPSF);
    bias2[idx] = b2[idx] * inv + be2[idx] - m2[idx] * inv;
  }
}

// ---------------- fused heads kernel ----------------
// Per block: model mdl, rows rb*64 .. rb*64+63 (row = b*2048+s flattened).
// Layer1: 64x256 output, K=4096, bf16 MFMA, A(h fp32) + B(w1' bf16) staged in LDS.
// Layer2: 64x128, K=256, X1 from LDS, w2' frags direct from L2.
// Layer3: per-lane dot + shfl reduce.
__global__ __launch_bounds__(256) void fused_heads_kernel(
    const float* __restrict__ h,
    const unsigned short* __restrict__ w1f,
    const unsigned short* __restrict__ w2f,
    const float* __restrict__ bias1,
    const float* __restrict__ bias2,
    const float* __restrict__ w3,
    const float* __restrict__ b3,
    float* __restrict__ out) {
  // LDS layout: Abuf[2] @ 0/16384 (64x64 fp32 each, granule-swizzled)
  //             Bbuf[2] @ 32768/65536 (256x64 bf16 each, granule-swizzled)
  // post-loop:  X1 @ 0 (64x256 bf16 swizzled, 32 KB), part @ 32768 (4x64 fp32)
  __shared__ __align__(16) char lds[98304];

  const int tid = threadIdx.x;
  const int lane = tid & 63;
  const int wv = tid >> 6;       // wave 0..3 -> owns layer1 cols wv*64..
  const int l15 = lane & 15;
  const int lq = lane >> 4;

  const int bid = blockIdx.x;
  // XCD-aware: model 0 -> XCDs with (bid&7)<4, model 1 -> rest (bijective)
  const int mdl = (bid >> 2) & 1;
  const int rb = (bid >> 3) * 4 + (bid & 3);

  const float* hM = h + ((size_t)mdl * 8192 + (size_t)rb * 64) * 4096;
  const unsigned short* w1m = w1f + (size_t)mdl * (256 * 4096);

  f32x4 acc[4][4];
#pragma unroll
  for (int i = 0; i < 4; ++i)
#pragma unroll
    for (int j = 0; j < 4; ++j)
#pragma unroll
      for (int q = 0; q < 4; ++q) acc[i][j][q] = 0.f;

  auto stageA = [&](int buf, int kt) {
    const int k0 = kt * 64;
    char* base = lds + buf * 16384;
#pragma unroll
    for (int is = 0; is < 4; ++is) {
      int o = is * 4096 + tid * 16;
      int row = o >> 8;            // 0..63 (256B per row: 64 fp32)
      int g = (o >> 4) & 15;       // LDS granule (16B = 4 fp32)
      // inverse-swizzled global source so that swizzled read sees linear k
      const float* src = hM + (size_t)row * 4096 + k0 + ((g ^ (row & 7)) << 2);
      gload_lds16((const void*)src, (void*)(base + o));
    }
  };
  auto stageB = [&](int buf, int kt) {
    const int k0 = kt * 64;
    char* base = lds + 32768 + buf * 32768;
#pragma unroll
    for (int is = 0; is < 8; ++is) {
      int o = is * 4096 + tid * 16;
      int n = o >> 7;              // 0..255 (128B per row: 64 bf16)
      int g = (o >> 4) & 7;        // LDS granule (16B = 8 bf16)
      const unsigned short* src = w1m + (size_t)n * 4096 + k0 + ((g ^ (n & 7)) << 3);
      gload_lds16((const void*)src, (void*)(base + o));
    }
  };

  stageA(0, 0);
  stageB(0, 0);
  __syncthreads();   // compiler drains vmcnt before barrier -> buf0 ready

  const int NKIT = 64;   // 4096 / 64
  for (int kt = 0; kt < NKIT; ++kt) {
    const int c = kt & 1;
    if (kt + 1 < NKIT) { stageA(c ^ 1, kt + 1); stageB(c ^ 1, kt + 1); }

    const char* Ab = lds + c * 16384;
    const char* Bb = lds + 32768 + c * 32768;
#pragma unroll
    for (int st = 0; st < 2; ++st) {
      const int k8 = st * 32 + lq * 8;     // lane's k-offset within BK
      bf16x8 aF[4], bF[4];
#pragma unroll
      for (int i = 0; i < 4; ++i) {
        int row = i * 16 + l15;
        int gA = k8 >> 2;                  // even
        f32x4 a0 = *(const f32x4*)(Ab + row * 256 + (((gA) ^ (row & 7)) << 4));
        f32x4 a1 = *(const f32x4*)(Ab + row * 256 + (((gA + 1) ^ (row & 7)) << 4));
        bf16x8 t;
        t[0] = (short)f2bf(a0[0]); t[1] = (short)f2bf(a0[1]);
        t[2] = (short)f2bf(a0[2]); t[3] = (short)f2bf(a0[3]);
        t[4] = (short)f2bf(a1[0]); t[5] = (short)f2bf(a1[1]);
        t[6] = (short)f2bf(a1[2]); t[7] = (short)f2bf(a1[3]);
        aF[i] = t;
      }
#pragma unroll
      for (int j = 0; j < 4; ++j) {
        int n = wv * 64 + j * 16 + l15;
        int gB = k8 >> 3;
        bF[j] = *(const bf16x8*)(Bb + n * 128 + (((gB) ^ (n & 7)) << 4));
      }
#pragma unroll
      for (int i = 0; i < 4; ++i)
#pragma unroll
        for (int j = 0; j < 4; ++j)
          acc[i][j] = __builtin_amdgcn_mfma_f32_16x16x32_bf16(aF[i], bF[j], acc[i][j], 0, 0, 0);
    }
    __syncthreads();   // all waves done reading buf c; staged buf c^1 drained
  }

  // ---- epilogue layer1: bias + relu -> X1 bf16 in LDS (swizzled) ----
  float b1v[4];
#pragma unroll
  for (int j = 0; j < 4; ++j) b1v[j] = bias1[mdl * 256 + wv * 64 + j * 16 + l15];
#pragma unroll
  for (int i = 0; i < 4; ++i) {
#pragma unroll
    for (int j = 0; j < 4; ++j) {
      int n = wv * 64 + j * 16 + l15;
#pragma unroll
      for (int q = 0; q < 4; ++q) {
        int row = i * 16 + lq * 4 + q;       // C layout: col=l15, row=lq*4+q
        float x = fmaxf(acc[i][j][q] + b1v[j], 0.f);
        *(unsigned short*)(lds + row * 512 + ((((n >> 3) ^ (row & 7)) << 4) | ((n & 7) << 1))) = f2bf(x);
      }
    }
  }
  __syncthreads();

  // ---- layer2: 64x128, K=256 over X1 ----
  f32x4 acc2[4][2];
#pragma unroll
  for (int i = 0; i < 4; ++i)
#pragma unroll
    for (int j = 0; j < 2; ++j)
#pragma unroll
      for (int q = 0; q < 4; ++q) acc2[i][j][q] = 0.f;

  const unsigned short* w2m = w2f + mdl * (128 * 256);
#pragma unroll
  for (int st = 0; st < 8; ++st) {
    int k8 = st * 32 + lq * 8;
    bf16x8 aX[4], bW[2];
#pragma unroll
    for (int i = 0; i < 4; ++i) {
      int row = i * 16 + l15;
      aX[i] = *(const bf16x8*)(lds + row * 512 + ((((k8 >> 3) ^ (row & 7)) << 4)));
    }
#pragma unroll
    for (int j = 0; j < 2; ++j) {
      int n2 = wv * 32 + j * 16 + l15;
      bW[j] = *(const bf16x8*)(w2m + n2 * 256 + k8);   // L2-resident
    }
#pragma unroll
    for (int i = 0; i < 4; ++i)
#pragma unroll
      for (int j = 0; j < 2; ++j)
        acc2[i][j] = __builtin_amdgcn_mfma_f32_16x16x32_bf16(aX[i], bW[j], acc2[i][j], 0, 0, 0);
  }

  // ---- layer3: relu(x2)*w3 dot, lane-group reduce, cross-wave reduce ----
  float w3v[2], b2v[2];
#pragma unroll
  for (int j = 0; j < 2; ++j) {
    int n2 = wv * 32 + j * 16 + l15;
    w3v[j] = w3[mdl * 128 + n2];
    b2v[j] = bias2[mdl * 128 + n2];
  }
  float* part = (float*)(lds + 32768);   // [4][64]
#pragma unroll
  for (int i = 0; i < 4; ++i) {
#pragma unroll
    for (int q = 0; q < 4; ++q) {
      float val = 0.f;
#pragma unroll
      for (int j = 0; j < 2; ++j) {
        float x = fmaxf(acc2[i][j][q] + b2v[j], 0.f);
        val += x * w3v[j];
      }
#pragma unroll
      for (int mk = 1; mk < 16; mk <<= 1) val += __shfl_xor(val, mk, 64);
      if (l15 == 0) part[wv * 64 + i * 16 + lq * 4 + q] = val;
    }
  }
  __syncthreads();
  if (tid < 64) {
    float s = part[tid] + part[64 + tid] + part[128 + tid] + part[192 + tid] + b3[mdl];
    out[((size_t)(rb * 64 + tid)) * 2 + mdl] = s;
  }
}

extern "C" void kernel_launch(void* const* d_in, const int* in_sizes, int n_in,
                              void* d_out, int out_size, void* d_ws, size_t ws_size,
                              hipStream_t stream) {
  const float* h   = (const float*)d_in[0];
  const float* w1  = (const float*)d_in[1];
  const float* b1  = (const float*)d_in[2];
  const float* g1  = (const float*)d_in[3];
  const float* be1 = (const float*)d_in[4];
  const float* m1  = (const float*)d_in[5];
  const float* v1  = (const float*)d_in[6];
  const float* w2  = (const float*)d_in[7];
  const float* b2  = (const float*)d_in[8];
  const float* g2  = (const float*)d_in[9];
  const float* be2 = (const float*)d_in[10];
  const float* m2  = (const float*)d_in[11];
  const float* v2  = (const float*)d_in[12];
  const float* w3  = (const float*)d_in[13];
  const float* b3  = (const float*)d_in[14];

  char* ws = (char*)d_ws;
  unsigned short* w1f = (unsigned short*)ws;               // 2*256*4096*2 = 4 MiB
  unsigned short* w2f = (unsigned short*)(ws + 4194304);   // 2*128*256*2  = 128 KiB
  float* bias1 = (float*)(ws + 4325376);                   // 512 fp32
  float* bias2 = (float*)(ws + 4327424);                   // 256 fp32

  prep_kernel<<<1024, 256, 0, stream>>>(w1, b1, g1, be1, m1, v1,
                                        w2, b2, g2, be2, m2, v2,
                                        w1f, w2f, bias1, bias2);
  fused_heads_kernel<<<256, 256, 0, stream>>>(h, w1f, w2f, bias1, bias2, w3, b3,
                                              (float*)d_out);
}